// Round 10
// baseline (257.542 us; speedup 1.0000x reference)
//
#include <hip/hip_runtime.h>
#include <hip/hip_bf16.h>
#include <math.h>

constexpr int N_ = 64, C_ = 64, T_ = 256, V_ = 25;
constexpr int L_ = 3, S_ = 3, IC_ = 16, K_ = 5;
constexpr int TT = 8, TB = T_ / TT;          // 32 t-blocks
constexpr int CHTV = T_ * V_;                // 6400 floats per channel plane

// 1/sqrt(1+1e-5)
#define RS 0.99999500003750f

using bf16x8 = __attribute__((ext_vector_type(8))) short;
using f32x16 = __attribute__((ext_vector_type(16))) float;

union FRG { uint4 q; bf16x8 b; unsigned int u[4]; };

__device__ __forceinline__ unsigned short bfr(float f) {
    __hip_bfloat16 h = __float2bfloat16(f);
    return *reinterpret_cast<unsigned short*>(&h);
}
__device__ __forceinline__ float bff(unsigned short u) {
    __hip_bfloat16 h;
    *reinterpret_cast<unsigned short*>(&h) = u;
    return __bfloat162float(h);
}
__device__ __forceinline__ unsigned int bfpk(float a, float b) {
    return (unsigned int)bfr(a) | ((unsigned int)bfr(b) << 16);
}
__device__ __forceinline__ float bfhi(unsigned int u) {
    unsigned int b = u & 0xffff0000u;
    return *reinterpret_cast<float*>(&b);
}
__device__ __forceinline__ float bflo(unsigned int u) {
    unsigned int b = u << 16;
    return *reinterpret_cast<float*>(&b);
}

// k-axis channel permutation (phase-1 GEMM): slot q (0..31) in half h -> ch.
// Chosen so q<24 == exactly the 24 epilogue-residual channels of half h.
__device__ __host__ __forceinline__ int chmap(int q, int h) {
    return (q >> 2) * 8 + h * 4 + (q & 3);
}

// ---------------------------------------------------------------------------
// k_prep: build MFMA lane-layout fragment tables (32x32x16 bf16).
// A-op: row = lane&31, k = (lane>>5)*8 + jj.  B-op: col = lane&31, same k.
// C/D: col = lane&31, row = (reg&3)+8*(reg>>2)+4*(lane>>5)
// WdF uses the chmap k-permutation (must match k_main's xv order).
// ---------------------------------------------------------------------------
__global__ void k_prep(const float* __restrict__ A,
                       const float* __restrict__ w_down,
                       const float* __restrict__ w_sub,
                       const float* __restrict__ g_sub,
                       const float* __restrict__ b_sub,
                       const float* __restrict__ bt_sub,
                       unsigned int* __restrict__ AdjF,
                       unsigned int* __restrict__ WdF,
                       unsigned int* __restrict__ WsubF,
                       float* __restrict__ SK) {
    const int tid = threadIdx.x;
    for (int e = tid; e < L_ * S_ * 2 * 64; e += 256) {
        int l = e & 63, ks = (e >> 6) & 1, ij = e >> 7;
        int v = l & 31, h = l >> 5;
        for (int dd = 0; dd < 4; ++dd) {
            float f[2];
            for (int s = 0; s < 2; ++s) {
                int u = ks * 16 + h * 8 + dd * 2 + s;
                f[s] = (v < V_ && u < V_) ? A[(ij * V_ + v) * V_ + u] : 0.f;
            }
            AdjF[e * 4 + dd] = bfpk(f[0], f[1]);
        }
    }
    for (int e = tid; e < 2 * 4 * 2 * 64; e += 256) {
        int l = e & 63, hl = (e >> 6) & 1, ks = (e >> 7) & 3, nt = e >> 9;
        int col = nt * 32 + (l & 31), h = l >> 5;
        for (int dd = 0; dd < 4; ++dd) {
            float f[2];
            for (int s = 0; s < 2; ++s) {
                int q = ks * 8 + dd * 2 + s;
                int ch = chmap(q, h);                       // permuted k-axis
                float w0 = (col < 48) ? w_down[col * C_ + ch] : 0.f;
                float whi = bff(bfr(w0));
                f[s] = hl ? (w0 - whi) : w0;
            }
            WdF[e * 4 + dd] = bfpk(f[0], f[1]);
        }
    }
    for (int e = tid; e < L_ * S_ * 64; e += 256) {
        int l = e & 63, ij = e >> 6;
        int o = l & 31, h = l >> 5;
        for (int dd = 0; dd < 4; ++dd) {
            float f[2];
            for (int s = 0; s < 2; ++s) {
                int c = h * 8 + dd * 2 + s;
                float w0 = 0.f;
                if (o < IC_) {
                    float ss = g_sub[ij * IC_ + o] * RS;
                    w0 = w_sub[(ij * IC_ + o) * IC_ + c] * ss;
                }
                f[s] = w0;
            }
            WsubF[e * 4 + dd] = bfpk(f[0], f[1]);
        }
    }
    if (tid < S_ * IC_) {
        int j = tid / IC_, o = tid % IC_;
        float s = 0.f;
        for (int i = 0; i < L_; ++i) {
            int gi = (i * S_ + j) * IC_ + o;
            float ss = g_sub[gi] * RS;
            s += fmaf(b_sub[gi], ss, bt_sub[gi]);
        }
        SK[tid] = s;
    }
}

// ---------------------------------------------------------------------------
// k_main: R9 structure; only change vs R9: __launch_bounds__(256, 6) so the
// LDS-permitted 6 blocks/CU (24 waves, 75% occ) is actually reachable.
// ---------------------------------------------------------------------------
__global__ __launch_bounds__(256, 6)
void k_main(const float* __restrict__ x,
            const unsigned int* __restrict__ AdjF,
            const unsigned int* __restrict__ WdF,
            const unsigned int* __restrict__ WsubF,
            const float* __restrict__ SK,
            const float* __restrict__ g_down,
            const float* __restrict__ b_down,
            const float* __restrict__ bt_down,
            const float* __restrict__ g_bn,
            const float* __restrict__ b_bn,
            float* __restrict__ out,
            float* __restrict__ partial) {
    __shared__ unsigned short s_xd[L_][TT][32][16];   // 24 KB bf16 xd
    __shared__ float s_cf[48][2];                     // final-BN coefs

    const int tid = threadIdx.x;
    const int w = tid >> 6, l = tid & 63;
    const int v = l & 31, h = l >> 5;
    const int n = blockIdx.x / TB, tb = blockIdx.x % TB;   // n-major
    const int t0 = tb * TT;
    const bool act = v < V_;
    const int vc = v < 24 ? v : 24;    // clamp pad lanes

    if (tid < 48) {
        float sb = g_bn[tid] * RS;
        s_cf[tid][0] = sb;
        s_cf[tid][1] = fmaf(SK[tid], sb, b_bn[tid]);
    }

    float xres[2][24];   // residual x for epilogue (q<24 slots), per mt

    // ---- phase 1: down-conv GEMM, split-bf16, one mt at a time ----
#pragma unroll
    for (int mt = 0; mt < 2; ++mt) {
        const int t = 2 * w + mt;
        const size_t xb = (size_t)n * C_ * CHTV + (size_t)(t0 + t) * V_ + vc;
        float xv[32];
#pragma unroll
        for (int q = 0; q < 32; ++q)
            xv[q] = x[xb + (size_t)chmap(q, h) * CHTV];
#pragma unroll
        for (int q = 0; q < 24; ++q) xres[mt][q] = xv[q];
        f32x16 acc[2];
#pragma unroll
        for (int nt = 0; nt < 2; ++nt)
#pragma unroll
            for (int q = 0; q < 16; ++q) acc[nt][q] = 0.f;
#pragma unroll
        for (int ks = 0; ks < 4; ++ks) {
            FRG ah, al;
#pragma unroll
            for (int dd = 0; dd < 4; ++dd) {
                float f0 = xv[ks * 8 + dd * 2], f1 = xv[ks * 8 + dd * 2 + 1];
                unsigned short h0 = bfr(f0), h1 = bfr(f1);
                ah.u[dd] = (unsigned int)h0 | ((unsigned int)h1 << 16);
                al.u[dd] = bfpk(f0 - bff(h0), f1 - bff(h1));
            }
#pragma unroll
            for (int nt = 0; nt < 2; ++nt) {
                FRG bh, bl;
                bh.q = *(const uint4*)&WdF[((nt * 8 + ks * 2 + 0) * 64 + l) * 4];
                bl.q = *(const uint4*)&WdF[((nt * 8 + ks * 2 + 1) * 64 + l) * 4];
                acc[nt] = __builtin_amdgcn_mfma_f32_32x32x16_bf16(ah.b, bh.b, acc[nt], 0, 0, 0);
                acc[nt] = __builtin_amdgcn_mfma_f32_32x32x16_bf16(ah.b, bl.b, acc[nt], 0, 0, 0);
                acc[nt] = __builtin_amdgcn_mfma_f32_32x32x16_bf16(al.b, bh.b, acc[nt], 0, 0, 0);
            }
        }
        // BN + ReLU -> s_xd (bf16)
#pragma unroll
        for (int nt = 0; nt < 2; ++nt) {
            const int col = nt * 32 + (l & 31);
            if (col < 48) {
                float sd = g_down[col] * RS;
                float bd = fmaf(b_down[col], sd, bt_down[col]);
                const int i_ = col >> 4, c_ = col & 15;
#pragma unroll
                for (int r = 0; r < 16; ++r) {
                    float x0 = fmaxf(fmaf(acc[nt][r], sd, bd), 0.f);
                    int vr = (r & 3) + 8 * (r >> 2) + 4 * h;
                    s_xd[i_][t][vr][c_] = bfr(x0);
                }
            }
        }
    }
    __syncthreads();   // the ONLY barrier

    // ---- edge partials from bf16 s_xd (fp32 sums; layout [i][n][tb][vv*16+c]) ----
    if (tid < 150) {
        const int i_ = tid / 50, rr = tid % 50;
        const int vv = rr >> 1, cg = rr & 1;
        float a8[8];
#pragma unroll
        for (int q = 0; q < 8; ++q) a8[q] = 0.f;
#pragma unroll
        for (int q = 0; q < TT; ++q) {
            uint4 pk = *(const uint4*)&s_xd[i_][q][vv][cg * 8];
            a8[0] += bflo(pk.x); a8[1] += bfhi(pk.x);
            a8[2] += bflo(pk.y); a8[3] += bfhi(pk.y);
            a8[4] += bflo(pk.z); a8[5] += bfhi(pk.z);
            a8[6] += bflo(pk.w); a8[7] += bfhi(pk.w);
        }
        float* pp = &partial[(((size_t)i_ * N_ + n) * TB + tb) * (IC_ * V_) + vv * 16 + cg * 8];
        *(float4*)pp       = make_float4(a8[0], a8[1], a8[2], a8[3]);
        *(float4*)(pp + 4) = make_float4(a8[4], a8[5], a8[6], a8[7]);
    }

    // ---- phase 2 (j-outer), transposed output, register-residual epilogue ----
    FRG xf[L_][2];
#pragma unroll
    for (int i_ = 0; i_ < L_; ++i_) {
        xf[i_][0].q = *(const uint4*)&s_xd[i_][2 * w + 0][v][h * 8];
        xf[i_][1].q = *(const uint4*)&s_xd[i_][2 * w + 1][v][h * 8];
    }

#pragma unroll
    for (int j = 0; j < S_; ++j) {
        f32x16 Y[2];
#pragma unroll
        for (int mt = 0; mt < 2; ++mt)
#pragma unroll
            for (int q = 0; q < 16; ++q) Y[mt][q] = 0.f;

#pragma unroll
        for (int i_ = 0; i_ < L_; ++i_) {
            FRG wf, af0, af1;
            wf.q  = *(const uint4*)&WsubF[((i_ * 3 + j) * 64 + l) * 4];
            af0.q = *(const uint4*)&AdjF[(((i_ * 3 + j) * 2 + 0) * 64 + l) * 4];
            af1.q = *(const uint4*)&AdjF[(((i_ * 3 + j) * 2 + 1) * 64 + l) * 4];
#pragma unroll
            for (int mt = 0; mt < 2; ++mt) {
                f32x16 m2;
#pragma unroll
                for (int q = 0; q < 16; ++q) m2[q] = 0.f;
                m2 = __builtin_amdgcn_mfma_f32_32x32x16_bf16(xf[i_][mt].b, wf.b, m2, 0, 0, 0);
                unsigned int P0[4], P1[4];
#pragma unroll
                for (int q = 0; q < 4; ++q) {
                    P0[q] = bfpk(m2[4 * q + 0], m2[4 * q + 1]);
                    P1[q] = bfpk(m2[4 * q + 2], m2[4 * q + 3]);
                }
#pragma unroll
                for (int ks = 0; ks < 2; ++ks) {
                    unsigned int a0 = P0[2 * ks], b0 = P0[2 * ks + 1];
                    unsigned int a1 = P1[2 * ks], b1 = P1[2 * ks + 1];
                    asm volatile("v_permlane32_swap_b32 %0, %1" : "+v"(a0), "+v"(b0));
                    asm volatile("v_permlane32_swap_b32 %0, %1" : "+v"(a1), "+v"(b1));
                    FRG bfv;
                    bfv.u[0] = a0; bfv.u[1] = a1; bfv.u[2] = b0; bfv.u[3] = b1;
                    // operand-swapped: D = bfv * Adj -> Y^T (col=v, row=chn)
                    Y[mt] = __builtin_amdgcn_mfma_f32_32x32x16_bf16(
                        bfv.b, (ks == 0 ? af0.b : af1.b), Y[mt], 0, 0, 0);
                }
            }
        }
        // epilogue: lane=v contiguous stores; residual from registers
        if (act) {
#pragma unroll
            for (int mt = 0; mt < 2; ++mt) {
                const int t = 2 * w + mt;
#pragma unroll
                for (int r = 0; r < 8; ++r) {
                    const int row = (r & 3) + 8 * (r >> 2) + 4 * h;   // 0..15
                    const int chn = j * IC_ + row;
                    const int qres = j * 8 + (r >> 2) * 4 + (r & 3);  // 0..23
                    const float a = s_cf[chn][0], b = s_cf[chn][1];
                    const size_t ob = ((size_t)(n * C_ + chn) * T_ + t0 + t) * V_ + v;
                    float val = fmaf(Y[mt][r], a, b) + xres[mt][qres];
                    out[ob] = fmaxf(val, 0.f);
                }
            }
        }
    }
}

// ---------------------------------------------------------------------------
// k_edge: grid = (n, i) = 192 blocks; per-layer edge conv -> esum_i[i][n][400]
// ---------------------------------------------------------------------------
__global__ __launch_bounds__(256, 2)
void k_edge(const float* __restrict__ partial,
            const float* __restrict__ w_edge,
            const float* __restrict__ g_edge,
            const float* __restrict__ bt_edge,
            float* __restrict__ esum) {
    __shared__ float s_xt[V_][IC_];
    __shared__ float s_in[V_][V_];
    __shared__ int   s_id[V_][K_];
    __shared__ float s_we[IC_][2 * IC_];
    __shared__ float s_se[IC_], s_be[IC_];
    const int tid = threadIdx.x;
    const int n = blockIdx.x & 63, i = blockIdx.x >> 6;

    for (int e = tid; e < IC_ * 2 * IC_; e += 256)
        ((float*)s_we)[e] = w_edge[i * IC_ * 2 * IC_ + e];
    if (tid < IC_) {
        s_se[tid] = g_edge[i * IC_ + tid] * RS;
        s_be[tid] = bt_edge[i * IC_ + tid];
    }
    for (int e = tid; e < IC_ * V_; e += 256) {
        int c = e & 15, v = e >> 4;
        float s = 0.f;
        for (int tb = 0; tb < TB; ++tb)
            s += partial[(((size_t)i * N_ + n) * TB + tb) * (IC_ * V_) + e];
        s_xt[v][c] = s * (1.f / T_);
    }
    __syncthreads();
    for (int e = tid; e < V_ * V_; e += 256) {
        int v = e / V_, u = e % V_;
        float s = 0.f;
#pragma unroll
        for (int c = 0; c < IC_; ++c) s += s_xt[v][c] * s_xt[u][c];
        s_in[v][u] = s;
    }
    __syncthreads();
    if (tid < V_) {
        int v = tid;
        float xxv = s_in[v][v];
        unsigned mask = 0;
        for (int k = 0; k < K_; ++k) {
            float best = -1e30f; int bi = 0;
            for (int u = 0; u < V_; ++u) {
                if (mask & (1u << u)) continue;
                float pd = 2.f * s_in[v][u] - xxv - s_in[u][u];
                if (pd > best) { best = pd; bi = u; }   // tie -> lowest u
            }
            mask |= 1u << bi;
            s_id[v][k] = bi;
        }
    }
    __syncthreads();
#pragma unroll 2
    for (int rep = 0; rep < 2; ++rep) {
        int e = tid + rep * 256;
        if (e < IC_ * V_) {
            int o = e / V_, v = e % V_;
            float bse = 0.f;
#pragma unroll
            for (int c = 0; c < IC_; ++c)
                bse += s_xt[v][c] * (s_we[o][IC_ + c] - s_we[o][c]);
            float m = -1e30f;
#pragma unroll
            for (int k = 0; k < K_; ++k) {
                int u = s_id[v][k];
                float s = bse;
#pragma unroll
                for (int c = 0; c < IC_; ++c) s += s_xt[u][c] * s_we[o][c];
                float hb = fmaf(s, s_se[o], s_be[o]);
                hb = hb >= 0.f ? hb : 0.2f * hb;
                m = fmaxf(m, hb);
            }
            esum[((size_t)i * N_ + n) * (IC_ * V_) + e] = m;
        }
    }
}

// ---------------------------------------------------------------------------
// k_edge_out: out channels 48..63 = relu(bn(sum_i esum_i) + x)
// ---------------------------------------------------------------------------
__global__ __launch_bounds__(256)
void k_edge_out(const float* __restrict__ x,
                const float* __restrict__ esum,
                const float* __restrict__ g_bn,
                const float* __restrict__ b_bn,
                float* __restrict__ out) {
    const int gid = blockIdx.x * 256 + threadIdx.x;     // [0, 64*16*1600)
    const int n = gid / (IC_ * 1600);
    const int r = gid % (IC_ * 1600);
    const int o = r / 1600;
    const int q = r % 1600;
    const int chn = 48 + o;
    const size_t fo = ((size_t)n * C_ + chn) * 1600 + q;   // float4 index
    float4 xv = ((const float4*)x)[fo];
    float sb = g_bn[chn] * RS;
    float bb = b_bn[chn];
    const float* e0 = &esum[((size_t)0 * N_ + n) * (IC_ * V_) + o * V_];
    const float* e1 = &esum[((size_t)1 * N_ + n) * (IC_ * V_) + o * V_];
    const float* e2 = &esum[((size_t)2 * N_ + n) * (IC_ * V_) + o * V_];
    float4 ov;
    {
        int p = q * 4;
        int i0 = p % V_, i1 = (p + 1) % V_, i2 = (p + 2) % V_, i3 = (p + 3) % V_;
        float s0 = e0[i0] + e1[i0] + e2[i0];
        float s1 = e0[i1] + e1[i1] + e2[i1];
        float s2 = e0[i2] + e1[i2] + e2[i2];
        float s3 = e0[i3] + e1[i3] + e2[i3];
        ov.x = fmaxf(fmaf(s0, sb, bb) + xv.x, 0.f);
        ov.y = fmaxf(fmaf(s1, sb, bb) + xv.y, 0.f);
        ov.z = fmaxf(fmaf(s2, sb, bb) + xv.z, 0.f);
        ov.w = fmaxf(fmaf(s3, sb, bb) + xv.w, 0.f);
    }
    ((float4*)out)[fo] = ov;
}

// ---------------------------------------------------------------------------
extern "C" void kernel_launch(void* const* d_in, const int* in_sizes, int n_in,
                              void* d_out, int out_size, void* d_ws, size_t ws_size,
                              hipStream_t stream) {
    (void)in_sizes; (void)n_in; (void)out_size; (void)ws_size;
    const float* x       = (const float*)d_in[0];
    const float* A       = (const float*)d_in[1];
    const float* w_down  = (const float*)d_in[2];
    const float* b_down  = (const float*)d_in[3];
    const float* g_down  = (const float*)d_in[4];
    const float* bt_down = (const float*)d_in[5];
    const float* w_sub   = (const float*)d_in[6];
    const float* b_sub   = (const float*)d_in[7];
    const float* g_sub   = (const float*)d_in[8];
    const float* bt_sub  = (const float*)d_in[9];
    const float* w_edge  = (const float*)d_in[10];
    const float* g_edge  = (const float*)d_in[11];
    const float* bt_edge = (const float*)d_in[12];
    const float* g_bn    = (const float*)d_in[13];
    const float* b_bn    = (const float*)d_in[14];
    float* out = (float*)d_out;

    unsigned int* AdjF  = (unsigned int*)d_ws;                 // 4608 dw
    unsigned int* WdF   = AdjF + L_ * S_ * 2 * 64 * 4;         // 4096 dw
    unsigned int* WsubF = WdF + 2 * 4 * 2 * 64 * 4;            // 2304 dw
    float* SK           = (float*)(WsubF + L_ * S_ * 64 * 4);  // 48 (+pad)
    float* partial      = SK + 64;                             // [3][64][32][400]
    float* esum         = partial + (size_t)L_ * N_ * TB * IC_ * V_;  // [3][64][400]

    hipLaunchKernelGGL(k_prep, dim3(1), dim3(256), 0, stream,
                       A, w_down, w_sub, g_sub, b_sub, bt_sub,
                       AdjF, WdF, WsubF, SK);
    hipLaunchKernelGGL(k_main, dim3(N_ * TB), dim3(256), 0, stream,
                       x, AdjF, WdF, WsubF, SK,
                       g_down, b_down, bt_down, g_bn, b_bn, out, partial);
    hipLaunchKernelGGL(k_edge, dim3(L_ * N_), dim3(256), 0, stream,
                       partial, w_edge, g_edge, bt_edge, esum);
    hipLaunchKernelGGL(k_edge_out, dim3(N_ * IC_ * 1600 / 256), dim3(256), 0, stream,
                       x, esum, g_bn, b_bn, out);
}

// Round 11
// 111.214 us; speedup vs baseline: 2.3157x; 2.3157x over previous
//
#include <hip/hip_runtime.h>
#include <hip/hip_bf16.h>
#include <math.h>

constexpr int N_ = 64, C_ = 64, T_ = 256, V_ = 25;
constexpr int L_ = 3, S_ = 3, IC_ = 16, K_ = 5;
constexpr int TT = 8, TB = T_ / TT;          // 32 t-blocks
constexpr int CHTV = T_ * V_;                // 6400 floats per channel plane

// 1/sqrt(1+1e-5)
#define RS 0.99999500003750f

using bf16x8 = __attribute__((ext_vector_type(8))) short;
using f32x16 = __attribute__((ext_vector_type(16))) float;

union FRG { uint4 q; bf16x8 b; unsigned int u[4]; };

__device__ __forceinline__ unsigned short bfr(float f) {
    __hip_bfloat16 h = __float2bfloat16(f);
    return *reinterpret_cast<unsigned short*>(&h);
}
__device__ __forceinline__ float bff(unsigned short u) {
    __hip_bfloat16 h;
    *reinterpret_cast<unsigned short*>(&h) = u;
    return __bfloat162float(h);
}
__device__ __forceinline__ unsigned int bfpk(float a, float b) {
    return (unsigned int)bfr(a) | ((unsigned int)bfr(b) << 16);
}
__device__ __forceinline__ float bfhi(unsigned int u) {
    unsigned int b = u & 0xffff0000u;
    return *reinterpret_cast<float*>(&b);
}
__device__ __forceinline__ float bflo(unsigned int u) {
    unsigned int b = u << 16;
    return *reinterpret_cast<float*>(&b);
}

// k-axis channel permutation (phase-1 GEMM): slot q (0..31) in half h -> ch.
// (Contraction is permutation-invariant; kept from R9 -- WdF matches.)
__device__ __host__ __forceinline__ int chmap(int q, int h) {
    return (q >> 2) * 8 + h * 4 + (q & 3);
}

// ---------------------------------------------------------------------------
// k_prep: build MFMA lane-layout fragment tables (32x32x16 bf16).
// A-op: row = lane&31, k = (lane>>5)*8 + jj.  B-op: col = lane&31, same k.
// C/D: col = lane&31, row = (reg&3)+8*(reg>>2)+4*(lane>>5)
// WdF uses the chmap k-permutation (must match k_main's xv order).
// ---------------------------------------------------------------------------
__global__ void k_prep(const float* __restrict__ A,
                       const float* __restrict__ w_down,
                       const float* __restrict__ w_sub,
                       const float* __restrict__ g_sub,
                       const float* __restrict__ b_sub,
                       const float* __restrict__ bt_sub,
                       unsigned int* __restrict__ AdjF,
                       unsigned int* __restrict__ WdF,
                       unsigned int* __restrict__ WsubF,
                       float* __restrict__ SK) {
    const int tid = threadIdx.x;
    for (int e = tid; e < L_ * S_ * 2 * 64; e += 256) {
        int l = e & 63, ks = (e >> 6) & 1, ij = e >> 7;
        int v = l & 31, h = l >> 5;
        for (int dd = 0; dd < 4; ++dd) {
            float f[2];
            for (int s = 0; s < 2; ++s) {
                int u = ks * 16 + h * 8 + dd * 2 + s;
                f[s] = (v < V_ && u < V_) ? A[(ij * V_ + v) * V_ + u] : 0.f;
            }
            AdjF[e * 4 + dd] = bfpk(f[0], f[1]);
        }
    }
    for (int e = tid; e < 2 * 4 * 2 * 64; e += 256) {
        int l = e & 63, hl = (e >> 6) & 1, ks = (e >> 7) & 3, nt = e >> 9;
        int col = nt * 32 + (l & 31), h = l >> 5;
        for (int dd = 0; dd < 4; ++dd) {
            float f[2];
            for (int s = 0; s < 2; ++s) {
                int q = ks * 8 + dd * 2 + s;
                int ch = chmap(q, h);                       // permuted k-axis
                float w0 = (col < 48) ? w_down[col * C_ + ch] : 0.f;
                float whi = bff(bfr(w0));
                f[s] = hl ? (w0 - whi) : w0;
            }
            WdF[e * 4 + dd] = bfpk(f[0], f[1]);
        }
    }
    for (int e = tid; e < L_ * S_ * 64; e += 256) {
        int l = e & 63, ij = e >> 6;
        int o = l & 31, h = l >> 5;
        for (int dd = 0; dd < 4; ++dd) {
            float f[2];
            for (int s = 0; s < 2; ++s) {
                int c = h * 8 + dd * 2 + s;
                float w0 = 0.f;
                if (o < IC_) {
                    float ss = g_sub[ij * IC_ + o] * RS;
                    w0 = w_sub[(ij * IC_ + o) * IC_ + c] * ss;
                }
                f[s] = w0;
            }
            WsubF[e * 4 + dd] = bfpk(f[0], f[1]);
        }
    }
    if (tid < S_ * IC_) {
        int j = tid / IC_, o = tid % IC_;
        float s = 0.f;
        for (int i = 0; i < L_; ++i) {
            int gi = (i * S_ + j) * IC_ + o;
            float ss = g_sub[gi] * RS;
            s += fmaf(b_sub[gi], ss, bt_sub[gi]);
        }
        SK[tid] = s;
    }
}

// ---------------------------------------------------------------------------
// k_main: R9 structure; ONE change vs R9: xres[2][24] register block deleted,
// epilogue re-reads x at lane-contiguous addresses (L3-hot, ~48 fewer VGPRs
// live across phase 2 -> occupancy rises without allocator coercion).
// ---------------------------------------------------------------------------
__global__ __launch_bounds__(256, 4)
void k_main(const float* __restrict__ x,
            const unsigned int* __restrict__ AdjF,
            const unsigned int* __restrict__ WdF,
            const unsigned int* __restrict__ WsubF,
            const float* __restrict__ SK,
            const float* __restrict__ g_down,
            const float* __restrict__ b_down,
            const float* __restrict__ bt_down,
            const float* __restrict__ g_bn,
            const float* __restrict__ b_bn,
            float* __restrict__ out,
            float* __restrict__ partial) {
    __shared__ unsigned short s_xd[L_][TT][32][16];   // 24 KB bf16 xd
    __shared__ float s_cf[48][2];                     // final-BN coefs

    const int tid = threadIdx.x;
    const int w = tid >> 6, l = tid & 63;
    const int v = l & 31, h = l >> 5;
    const int n = blockIdx.x / TB, tb = blockIdx.x % TB;   // n-major
    const int t0 = tb * TT;
    const bool act = v < V_;
    const int vc = v < 24 ? v : 24;    // clamp pad lanes

    if (tid < 48) {
        float sb = g_bn[tid] * RS;
        s_cf[tid][0] = sb;
        s_cf[tid][1] = fmaf(SK[tid], sb, b_bn[tid]);
    }

    // ---- phase 1: down-conv GEMM, split-bf16, one mt at a time ----
#pragma unroll
    for (int mt = 0; mt < 2; ++mt) {
        const int t = 2 * w + mt;
        const size_t xb = (size_t)n * C_ * CHTV + (size_t)(t0 + t) * V_ + vc;
        float xv[32];
#pragma unroll
        for (int q = 0; q < 32; ++q)
            xv[q] = x[xb + (size_t)chmap(q, h) * CHTV];
        f32x16 acc[2];
#pragma unroll
        for (int nt = 0; nt < 2; ++nt)
#pragma unroll
            for (int q = 0; q < 16; ++q) acc[nt][q] = 0.f;
#pragma unroll
        for (int ks = 0; ks < 4; ++ks) {
            FRG ah, al;
#pragma unroll
            for (int dd = 0; dd < 4; ++dd) {
                float f0 = xv[ks * 8 + dd * 2], f1 = xv[ks * 8 + dd * 2 + 1];
                unsigned short h0 = bfr(f0), h1 = bfr(f1);
                ah.u[dd] = (unsigned int)h0 | ((unsigned int)h1 << 16);
                al.u[dd] = bfpk(f0 - bff(h0), f1 - bff(h1));
            }
#pragma unroll
            for (int nt = 0; nt < 2; ++nt) {
                FRG bh, bl;
                bh.q = *(const uint4*)&WdF[((nt * 8 + ks * 2 + 0) * 64 + l) * 4];
                bl.q = *(const uint4*)&WdF[((nt * 8 + ks * 2 + 1) * 64 + l) * 4];
                acc[nt] = __builtin_amdgcn_mfma_f32_32x32x16_bf16(ah.b, bh.b, acc[nt], 0, 0, 0);
                acc[nt] = __builtin_amdgcn_mfma_f32_32x32x16_bf16(ah.b, bl.b, acc[nt], 0, 0, 0);
                acc[nt] = __builtin_amdgcn_mfma_f32_32x32x16_bf16(al.b, bh.b, acc[nt], 0, 0, 0);
            }
        }
        // BN + ReLU -> s_xd (bf16)
#pragma unroll
        for (int nt = 0; nt < 2; ++nt) {
            const int col = nt * 32 + (l & 31);
            if (col < 48) {
                float sd = g_down[col] * RS;
                float bd = fmaf(b_down[col], sd, bt_down[col]);
                const int i_ = col >> 4, c_ = col & 15;
#pragma unroll
                for (int r = 0; r < 16; ++r) {
                    float x0 = fmaxf(fmaf(acc[nt][r], sd, bd), 0.f);
                    int vr = (r & 3) + 8 * (r >> 2) + 4 * h;
                    s_xd[i_][t][vr][c_] = bfr(x0);
                }
            }
        }
    }
    __syncthreads();   // the ONLY barrier

    // ---- edge partials from bf16 s_xd (fp32 sums; layout [i][n][tb][vv*16+c]) ----
    if (tid < 150) {
        const int i_ = tid / 50, rr = tid % 50;
        const int vv = rr >> 1, cg = rr & 1;
        float a8[8];
#pragma unroll
        for (int q = 0; q < 8; ++q) a8[q] = 0.f;
#pragma unroll
        for (int q = 0; q < TT; ++q) {
            uint4 pk = *(const uint4*)&s_xd[i_][q][vv][cg * 8];
            a8[0] += bflo(pk.x); a8[1] += bfhi(pk.x);
            a8[2] += bflo(pk.y); a8[3] += bfhi(pk.y);
            a8[4] += bflo(pk.z); a8[5] += bfhi(pk.z);
            a8[6] += bflo(pk.w); a8[7] += bfhi(pk.w);
        }
        float* pp = &partial[(((size_t)i_ * N_ + n) * TB + tb) * (IC_ * V_) + vv * 16 + cg * 8];
        *(float4*)pp       = make_float4(a8[0], a8[1], a8[2], a8[3]);
        *(float4*)(pp + 4) = make_float4(a8[4], a8[5], a8[6], a8[7]);
    }

    // ---- phase 2 (j-outer), transposed output; epilogue re-reads x (L3) ----
    FRG xf[L_][2];
#pragma unroll
    for (int i_ = 0; i_ < L_; ++i_) {
        xf[i_][0].q = *(const uint4*)&s_xd[i_][2 * w + 0][v][h * 8];
        xf[i_][1].q = *(const uint4*)&s_xd[i_][2 * w + 1][v][h * 8];
    }

#pragma unroll
    for (int j = 0; j < S_; ++j) {
        f32x16 Y[2];
#pragma unroll
        for (int mt = 0; mt < 2; ++mt)
#pragma unroll
            for (int q = 0; q < 16; ++q) Y[mt][q] = 0.f;

#pragma unroll
        for (int i_ = 0; i_ < L_; ++i_) {
            FRG wf, af0, af1;
            wf.q  = *(const uint4*)&WsubF[((i_ * 3 + j) * 64 + l) * 4];
            af0.q = *(const uint4*)&AdjF[(((i_ * 3 + j) * 2 + 0) * 64 + l) * 4];
            af1.q = *(const uint4*)&AdjF[(((i_ * 3 + j) * 2 + 1) * 64 + l) * 4];
#pragma unroll
            for (int mt = 0; mt < 2; ++mt) {
                f32x16 m2;
#pragma unroll
                for (int q = 0; q < 16; ++q) m2[q] = 0.f;
                m2 = __builtin_amdgcn_mfma_f32_32x32x16_bf16(xf[i_][mt].b, wf.b, m2, 0, 0, 0);
                unsigned int P0[4], P1[4];
#pragma unroll
                for (int q = 0; q < 4; ++q) {
                    P0[q] = bfpk(m2[4 * q + 0], m2[4 * q + 1]);
                    P1[q] = bfpk(m2[4 * q + 2], m2[4 * q + 3]);
                }
#pragma unroll
                for (int ks = 0; ks < 2; ++ks) {
                    unsigned int a0 = P0[2 * ks], b0 = P0[2 * ks + 1];
                    unsigned int a1 = P1[2 * ks], b1 = P1[2 * ks + 1];
                    asm volatile("v_permlane32_swap_b32 %0, %1" : "+v"(a0), "+v"(b0));
                    asm volatile("v_permlane32_swap_b32 %0, %1" : "+v"(a1), "+v"(b1));
                    FRG bfv;
                    bfv.u[0] = a0; bfv.u[1] = a1; bfv.u[2] = b0; bfv.u[3] = b1;
                    // operand-swapped: D = bfv * Adj -> Y^T (col=v, row=chn)
                    Y[mt] = __builtin_amdgcn_mfma_f32_32x32x16_bf16(
                        bfv.b, (ks == 0 ? af0.b : af1.b), Y[mt], 0, 0, 0);
                }
            }
        }
        // epilogue: lane=v contiguous stores; residual re-read (contiguous, L3)
        if (act) {
#pragma unroll
            for (int mt = 0; mt < 2; ++mt) {
                const int t = 2 * w + mt;
#pragma unroll
                for (int r = 0; r < 8; ++r) {
                    const int row = (r & 3) + 8 * (r >> 2) + 4 * h;   // 0..15
                    const int chn = j * IC_ + row;
                    const float a = s_cf[chn][0], b = s_cf[chn][1];
                    const size_t ob = ((size_t)(n * C_ + chn) * T_ + t0 + t) * V_ + v;
                    float val = fmaf(Y[mt][r], a, b) + x[ob];
                    out[ob] = fmaxf(val, 0.f);
                }
            }
        }
    }
}

// ---------------------------------------------------------------------------
// k_edge: grid = (n, i) = 192 blocks; per-layer edge conv -> esum_i[i][n][400]
// ---------------------------------------------------------------------------
__global__ __launch_bounds__(256, 2)
void k_edge(const float* __restrict__ partial,
            const float* __restrict__ w_edge,
            const float* __restrict__ g_edge,
            const float* __restrict__ bt_edge,
            float* __restrict__ esum) {
    __shared__ float s_xt[V_][IC_];
    __shared__ float s_in[V_][V_];
    __shared__ int   s_id[V_][K_];
    __shared__ float s_we[IC_][2 * IC_];
    __shared__ float s_se[IC_], s_be[IC_];
    const int tid = threadIdx.x;
    const int n = blockIdx.x & 63, i = blockIdx.x >> 6;

    for (int e = tid; e < IC_ * 2 * IC_; e += 256)
        ((float*)s_we)[e] = w_edge[i * IC_ * 2 * IC_ + e];
    if (tid < IC_) {
        s_se[tid] = g_edge[i * IC_ + tid] * RS;
        s_be[tid] = bt_edge[i * IC_ + tid];
    }
    for (int e = tid; e < IC_ * V_; e += 256) {
        int c = e & 15, v = e >> 4;
        float s = 0.f;
        for (int tb = 0; tb < TB; ++tb)
            s += partial[(((size_t)i * N_ + n) * TB + tb) * (IC_ * V_) + e];
        s_xt[v][c] = s * (1.f / T_);
    }
    __syncthreads();
    for (int e = tid; e < V_ * V_; e += 256) {
        int v = e / V_, u = e % V_;
        float s = 0.f;
#pragma unroll
        for (int c = 0; c < IC_; ++c) s += s_xt[v][c] * s_xt[u][c];
        s_in[v][u] = s;
    }
    __syncthreads();
    if (tid < V_) {
        int v = tid;
        float xxv = s_in[v][v];
        unsigned mask = 0;
        for (int k = 0; k < K_; ++k) {
            float best = -1e30f; int bi = 0;
            for (int u = 0; u < V_; ++u) {
                if (mask & (1u << u)) continue;
                float pd = 2.f * s_in[v][u] - xxv - s_in[u][u];
                if (pd > best) { best = pd; bi = u; }   // tie -> lowest u
            }
            mask |= 1u << bi;
            s_id[v][k] = bi;
        }
    }
    __syncthreads();
#pragma unroll 2
    for (int rep = 0; rep < 2; ++rep) {
        int e = tid + rep * 256;
        if (e < IC_ * V_) {
            int o = e / V_, v = e % V_;
            float bse = 0.f;
#pragma unroll
            for (int c = 0; c < IC_; ++c)
                bse += s_xt[v][c] * (s_we[o][IC_ + c] - s_we[o][c]);
            float m = -1e30f;
#pragma unroll
            for (int k = 0; k < K_; ++k) {
                int u = s_id[v][k];
                float s = bse;
#pragma unroll
                for (int c = 0; c < IC_; ++c) s += s_xt[u][c] * s_we[o][c];
                float hb = fmaf(s, s_se[o], s_be[o]);
                hb = hb >= 0.f ? hb : 0.2f * hb;
                m = fmaxf(m, hb);
            }
            esum[((size_t)i * N_ + n) * (IC_ * V_) + e] = m;
        }
    }
}

// ---------------------------------------------------------------------------
// k_edge_out: out channels 48..63 = relu(bn(sum_i esum_i) + x)
// ---------------------------------------------------------------------------
__global__ __launch_bounds__(256)
void k_edge_out(const float* __restrict__ x,
                const float* __restrict__ esum,
                const float* __restrict__ g_bn,
                const float* __restrict__ b_bn,
                float* __restrict__ out) {
    const int gid = blockIdx.x * 256 + threadIdx.x;     // [0, 64*16*1600)
    const int n = gid / (IC_ * 1600);
    const int r = gid % (IC_ * 1600);
    const int o = r / 1600;
    const int q = r % 1600;
    const int chn = 48 + o;
    const size_t fo = ((size_t)n * C_ + chn) * 1600 + q;   // float4 index
    float4 xv = ((const float4*)x)[fo];
    float sb = g_bn[chn] * RS;
    float bb = b_bn[chn];
    const float* e0 = &esum[((size_t)0 * N_ + n) * (IC_ * V_) + o * V_];
    const float* e1 = &esum[((size_t)1 * N_ + n) * (IC_ * V_) + o * V_];
    const float* e2 = &esum[((size_t)2 * N_ + n) * (IC_ * V_) + o * V_];
    float4 ov;
    {
        int p = q * 4;
        int i0 = p % V_, i1 = (p + 1) % V_, i2 = (p + 2) % V_, i3 = (p + 3) % V_;
        float s0 = e0[i0] + e1[i0] + e2[i0];
        float s1 = e0[i1] + e1[i1] + e2[i1];
        float s2 = e0[i2] + e1[i2] + e2[i2];
        float s3 = e0[i3] + e1[i3] + e2[i3];
        ov.x = fmaxf(fmaf(s0, sb, bb) + xv.x, 0.f);
        ov.y = fmaxf(fmaf(s1, sb, bb) + xv.y, 0.f);
        ov.z = fmaxf(fmaf(s2, sb, bb) + xv.z, 0.f);
        ov.w = fmaxf(fmaf(s3, sb, bb) + xv.w, 0.f);
    }
    ((float4*)out)[fo] = ov;
}

// ---------------------------------------------------------------------------
extern "C" void kernel_launch(void* const* d_in, const int* in_sizes, int n_in,
                              void* d_out, int out_size, void* d_ws, size_t ws_size,
                              hipStream_t stream) {
    (void)in_sizes; (void)n_in; (void)out_size; (void)ws_size;
    const float* x       = (const float*)d_in[0];
    const float* A       = (const float*)d_in[1];
    const float* w_down  = (const float*)d_in[2];
    const float* b_down  = (const float*)d_in[3];
    const float* g_down  = (const float*)d_in[4];
    const float* bt_down = (const float*)d_in[5];
    const float* w_sub   = (const float*)d_in[6];
    const float* b_sub   = (const float*)d_in[7];
    const float* g_sub   = (const float*)d_in[8];
    const float* bt_sub  = (const float*)d_in[9];
    const float* w_edge  = (const float*)d_in[10];
    const float* g_edge  = (const float*)d_in[11];
    const float* bt_edge = (const float*)d_in[12];
    const float* g_bn    = (const float*)d_in[13];
    const float* b_bn    = (const float*)d_in[14];
    float* out = (float*)d_out;

    unsigned int* AdjF  = (unsigned int*)d_ws;                 // 4608 dw
    unsigned int* WdF   = AdjF + L_ * S_ * 2 * 64 * 4;         // 4096 dw
    unsigned int* WsubF = WdF + 2 * 4 * 2 * 64 * 4;            // 2304 dw
    float* SK           = (float*)(WsubF + L_ * S_ * 64 * 4);  // 48 (+pad)
    float* partial      = SK + 64;                             // [3][64][32][400]
    float* esum         = partial + (size_t)L_ * N_ * TB * IC_ * V_;  // [3][64][400]

    hipLaunchKernelGGL(k_prep, dim3(1), dim3(256), 0, stream,
                       A, w_down, w_sub, g_sub, b_sub, bt_sub,
                       AdjF, WdF, WsubF, SK);
    hipLaunchKernelGGL(k_main, dim3(N_ * TB), dim3(256), 0, stream,
                       x, AdjF, WdF, WsubF, SK,
                       g_down, b_down, bt_down, g_bn, b_bn, out, partial);
    hipLaunchKernelGGL(k_edge, dim3(L_ * N_), dim3(256), 0, stream,
                       partial, w_edge, g_edge, bt_edge, esum);
    hipLaunchKernelGGL(k_edge_out, dim3(N_ * IC_ * 1600 / 256), dim3(256), 0, stream,
                       x, esum, g_bn, b_bn, out);
}